// Round 9
// baseline (2057.001 us; speedup 1.0000x reference)
//
#include <hip/hip_runtime.h>
#include <hip/hip_fp16.h>

// Problem dims (fixed)
#define Bc 128   // batch
#define Tc 128   // timesteps
#define Nc 128   // driving series
#define Mc 256   // hidden
#define G4 1024  // 4*M

typedef _Float16 half8 __attribute__((ext_vector_type(8)));
typedef float f32x4 __attribute__((ext_vector_type(4)));
typedef unsigned u32x4 __attribute__((ext_vector_type(4)));

__device__ __forceinline__ float frcp(float x) {
#if __has_builtin(__builtin_amdgcn_rcpf)
  return __builtin_amdgcn_rcpf(x);
#else
  return 1.f / x;
#endif
}
__device__ __forceinline__ float fsig(float x) { return frcp(1.f + __expf(-x)); }
__device__ __forceinline__ float ftanh(float x) {
  float t = __expf(2.f * x);
  return 1.f - 2.f * frcp(t + 1.f);
}

// gfx950: offset:N must precede cache flags
#define LDX4CC(dst, ptr, OFF) \
  asm volatile("global_load_dwordx4 %0, %1, off offset:" #OFF " sc0 sc1" \
               : "=v"(dst) : "v"(ptr))
#define LDX4P(dst, ptr, OFF) \
  asm volatile("global_load_dwordx4 %0, %1, off offset:" #OFF \
               : "=v"(dst) : "v"(ptr))
#define STDWCC(ptr, v_) \
  asm volatile("global_store_dword %0, %1, off sc0 sc1" :: "v"(ptr), "v"(v_))
#define STDWP(ptr, v_) \
  asm volatile("global_store_dword %0, %1, off" :: "v"(ptr), "v"(v_))
#define VMCNTN(N) do { asm volatile("s_waitcnt vmcnt(" #N ")" ::: "memory"); \
                       __builtin_amdgcn_sched_barrier(0); } while (0)

// ---------------------------------------------------------------------------
// k_prep (8768 blocks x 256):
//  bid<512   : pack Wh -> fp16 A-frags, gate-interleaved cols j'=4m+g, and
//              k-pair order (r2, r2+4) matching the B-side u32 (m, m+4) pairs.
//  512..575  : hx2[0] = ~pack(fp16(h0))  (u32 i=4a+d <-> halves (8a+d, 8a+d+4))
//  576..8767 : zero hx2[1..128]  (poll sentinel; re-zeroed EVERY launch)
// ---------------------------------------------------------------------------
__global__ void k_prep(const float* __restrict__ Wh, const float* __restrict__ h0,
                       __half* __restrict__ wht, unsigned* __restrict__ hx2) {
  int bid = blockIdx.x;
  if (bid < 512) {
    int i = bid * 256 + threadIdx.x;       // u32 index in [0, 131072)
    int jt = i >> 11;
    int rem = i & 2047;
    int kt = rem >> 8;
    int rem2 = rem & 255;
    int lane = rem2 >> 2;
    int r2 = rem2 & 3;
    int jp = jt * 16 + (lane & 15);        // permuted col j'
    int g = jp & 3, mcol = jp >> 2;
    int j = g * 256 + mcol;                // original Wh column
    int mk0 = kt * 32 + (lane >> 4) * 8 + r2;   // k-pair (r2, r2+4)
    wht[(size_t)i * 2]     = __float2half(Wh[(size_t)mk0 * G4 + j]);
    wht[(size_t)i * 2 + 1] = __float2half(Wh[(size_t)(mk0 + 4) * G4 + j]);
  } else if (bid < 576) {
    int idx = (bid - 512) * 256 + threadIdx.x;   // 0..16383
    int b = idx >> 7, i = idx & 127;
    int a = i >> 2, d = i & 3;
    unsigned lo = __half_as_ushort(__float2half(h0[(size_t)b * Mc + 8 * a + d]));
    unsigned hi = __half_as_ushort(__float2half(h0[(size_t)b * Mc + 8 * a + d + 4]));
    hx2[idx] = ~(lo | (hi << 16));
  } else {
    int idx = (bid - 576) * 256 + threadIdx.x;   // 0..2097151
    hx2[16384 + idx] = 0u;
  }
}

// ---------------------------------------------------------------------------
// k_ux: PX[b][u][n] = exp(2*(sum_t X[b][t][n]*Ud[t][u] + bU[u]))
// ---------------------------------------------------------------------------
__global__ void k_ux(const float* __restrict__ X, const float* __restrict__ Ud,
                     const float* __restrict__ bU, float* __restrict__ PX) {
  __shared__ float Xl[Tc][Nc];  // 64KB
  int b = blockIdx.x;
  const float* Xb = X + (size_t)b * Tc * Nc;
  for (int i = threadIdx.x; i < Tc * Nc; i += 256) Xl[i >> 7][i & 127] = Xb[i];
  __syncthreads();
  int n = threadIdx.x & 127;
  int uh = __builtin_amdgcn_readfirstlane(threadIdx.x >> 7);
  for (int u0 = uh * 64; u0 < uh * 64 + 64; u0 += 8) {
    float acc[8];
#pragma unroll
    for (int i = 0; i < 8; i++) acc[i] = 0.f;
    for (int tt = 0; tt < Tc; ++tt) {
      float xv = Xl[tt][n];
#pragma unroll
      for (int i = 0; i < 8; i++) acc[i] += xv * Ud[tt * Tc + u0 + i];
    }
#pragma unroll
    for (int i = 0; i < 8; i++)
      PX[((size_t)b * Tc + (u0 + i)) * Nc + n] = __expf(2.f * (acc[i] + bU[u0 + i]));
  }
}

// ---------------------------------------------------------------------------
// k_xwx2: XWxP[t][b][j'] with j' = 4m+g. grid 512 = t(128) x bq(4), 256 thr.
// ---------------------------------------------------------------------------
__global__ __launch_bounds__(256, 2)
void k_xwx2(const float* __restrict__ X, const float* __restrict__ Wx,
            const float* __restrict__ bias, float* __restrict__ XWxP) {
  __shared__ float xl[32][Nc];  // 16KB
  int t = blockIdx.x >> 2;
  int b0 = (blockIdx.x & 3) * 32;
  for (int i = threadIdx.x; i < 32 * Nc; i += 256) {
    int row = i >> 7, n = i & 127;
    xl[row][n] = X[(size_t)(b0 + row) * Tc * Nc + (size_t)t * Nc + n];
  }
  __syncthreads();
  int m = threadIdx.x;
  float acc[32][4];
#pragma unroll
  for (int i = 0; i < 32; i++)
#pragma unroll
    for (int g = 0; g < 4; g++) acc[i][g] = 0.f;
  for (int n = 0; n < Nc; ++n) {
    float wi = Wx[(size_t)n * G4 + m];
    float wf = Wx[(size_t)n * G4 + 256 + m];
    float wg = Wx[(size_t)n * G4 + 512 + m];
    float wo = Wx[(size_t)n * G4 + 768 + m];
#pragma unroll
    for (int i = 0; i < 32; i++) {
      float xv = xl[i][n];
      acc[i][0] += xv * wi; acc[i][1] += xv * wf;
      acc[i][2] += xv * wg; acc[i][3] += xv * wo;
    }
  }
  float bi = bias[m], bf = bias[256 + m], bg = bias[512 + m], bo = bias[768 + m];
#pragma unroll
  for (int i = 0; i < 32; i++) {
    float4 o;
    o.x = acc[i][0] + bi; o.y = acc[i][1] + bf;
    o.z = acc[i][2] + bg; o.w = acc[i][3] + bo;
    *(float4*)(XWxP + ((size_t)t * Bc + b0 + i) * G4 + m * 4) = o;
  }
}

// ---------------------------------------------------------------------------
// k_scan: persistent LSTM scan, 8 blocks x 512 threads, 4 pipelined
// batch-groups per block (slot order g0..g3 per t). DATA-IS-FLAG protocol
// (proven r7/r8): h published as ~pack dword sc0sc1, slot pre-zeroed,
// consumer checks all dwords nonzero. A-frags (64 VGPR) shared by all groups.
// vmcnt ledger: 12 ops/slot (8 h-ld + 2 x-ld + 1 h-st + 1 c-st);
// steady VMCNTN(12) leaves {next-10, last-slot stores(2)} and drains the
// current group's 10 loads + 2-slot-old stores. Group's poll-loads are
// issued 3 slots (~2-3us) after its store -> first-poll success in steady
// state. Retry: re-issue + vmcnt(0) (rare; self-healing, ledger unaffected).
// Pointers advance at CONSUME so retry reads hq[G] directly.
// ---------------------------------------------------------------------------
#define ISSUE_H(BUF, PTR) \
  LDX4CC(hbuf[BUF][0], PTR, 0);   LDX4CC(hbuf[BUF][1], PTR, 64); \
  LDX4CC(hbuf[BUF][2], PTR, 128); LDX4CC(hbuf[BUF][3], PTR, 192); \
  LDX4CC(hbuf[BUF][4], PTR, 256); LDX4CC(hbuf[BUF][5], PTR, 320); \
  LDX4CC(hbuf[BUF][6], PTR, 384); LDX4CC(hbuf[BUF][7], PTR, 448);

#define SLOT(G, GN) \
  { \
    constexpr int cb_ = (G) & 1, nb_ = (GN) & 1; \
    /* prefetch next slot's group */ \
    ISSUE_H(nb_, hq[GN]); \
    LDX4P(xbuf[nb_][0], xq[GN], 0); LDX4P(xbuf[nb_][1], xq[GN], 64); \
    if ((G) == 0 && t == 0) { VMCNTN(10); } else { VMCNTN(12); } \
    /* readiness: every dword of hbuf[cb_] nonzero */ \
    for (;;) { \
      unsigned mn_ = 0xFFFFFFFFu; \
      _Pragma("unroll") \
      for (int kt = 0; kt < 8; ++kt) { \
        u32x4 u_ = __builtin_bit_cast(u32x4, hbuf[cb_][kt]); \
        mn_ = min(mn_, min(min(u_.x, u_.y), min(u_.z, u_.w))); \
      } \
      if (__builtin_expect(mn_ != 0u, 1)) break; \
      __builtin_amdgcn_s_sleep(1); \
      ISSUE_H(cb_, hq[G]); \
      VMCNTN(0); \
    } \
    f32x4 acc0_ = xbuf[cb_][0], acc1_ = xbuf[cb_][1]; \
    _Pragma("unroll") \
    for (int kt = 0; kt < 8; ++kt) { \
      u32x4 u_ = ~__builtin_bit_cast(u32x4, hbuf[cb_][kt]); \
      half8 Bf_ = __builtin_bit_cast(half8, u_); \
      acc0_ = __builtin_amdgcn_mfma_f32_16x16x32_f16(A0[kt], Bf_, acc0_, 0, 0, 0); \
      acc1_ = __builtin_amdgcn_mfma_f32_16x16x32_f16(A1[kt], Bf_, acc1_, 0, 0, 0); \
    } \
    float i0_ = fsig(acc0_[0]), f0_ = fsig(acc0_[1]); \
    float g0_ = ftanh(acc0_[2]), o0_ = fsig(acc0_[3]); \
    c0g[G] = f0_ * c0g[G] + i0_ * g0_; \
    float h0_ = o0_ * ftanh(c0g[G]); \
    float i1_ = fsig(acc1_[0]), f1_ = fsig(acc1_[1]); \
    float g1_ = ftanh(acc1_[2]), o1_ = fsig(acc1_[3]); \
    c1g[G] = f1_ * c1g[G] + i1_ * g1_; \
    float h1_ = o1_ * ftanh(c1g[G]); \
    unsigned pk_ = (unsigned)__half_as_ushort(__float2half(h0_)) | \
                   ((unsigned)__half_as_ushort(__float2half(h1_)) << 16); \
    STDWCC(hs[G], ~pk_); \
    unsigned ck_ = (unsigned)__half_as_ushort(__float2half(c0g[G])) | \
                   ((unsigned)__half_as_ushort(__float2half(c1g[G])) << 16); \
    STDWP(cs[G], ck_); \
    hq[G] += 65536; xq[G] += 524288; hs[G] += 65536; cs[G] += 65536; \
  }

__global__ __launch_bounds__(512, 2)
void k_scan(const __half* __restrict__ wht, const float* __restrict__ xwxp,
            unsigned* __restrict__ hx2, unsigned* __restrict__ cx2,
            const float* __restrict__ s0) {
  int bid = blockIdx.x;                 // 8 blocks
  int set = bid >> 2, q = bid & 3;
  int tid = threadIdx.x;
  int wave = __builtin_amdgcn_readfirstlane(tid >> 6);
  int lane = tid & 63;
  int lb = lane & 15, lg = lane >> 4;
  int jt0 = q * 16 + wave * 2;          // even
  int m0 = jt0 * 4 + lg;

  // persistent A fragments: 64 VGPRs, loaded once, shared by all 4 groups
  half8 A0[8], A1[8];
#pragma unroll
  for (int kt = 0; kt < 8; ++kt) {
    A0[kt] = *(const half8*)(wht + ((size_t)(jt0 * 8 + kt) * 64 + lane) * 8);
    A1[kt] = *(const half8*)(wht + ((size_t)((jt0 + 1) * 8 + kt) * 64 + lane) * 8);
  }

  float c0g[4], c1g[4];
  const char* hq[4];
  const char* xq[4];
  char* hs[4];
  char* cs[4];
#pragma unroll
  for (int g = 0; g < 4; ++g) {
    int bg = set * 64 + g * 16 + lb;
    c0g[g] = s0[(size_t)bg * Mc + m0];
    c1g[g] = s0[(size_t)bg * Mc + m0 + 4];
    hq[g] = (const char*)hx2 + ((size_t)bg * 128 + lg * 4) * 4;
    hs[g] = (char*)hx2 + ((size_t)16384 + bg * 128 + jt0 * 2 + lg) * 4;
    xq[g] = (const char*)xwxp + ((size_t)bg * G4 + jt0 * 16 + lg * 4) * 4;
    cs[g] = (char*)cx2 + ((size_t)bg * 128 + jt0 * 2 + lg) * 4;
  }

  f32x4 hbuf[2][8];
  f32x4 xbuf[2][2];

  // drain compiler VMEM, then seed group 0 into buffer 0
  asm volatile("s_waitcnt vmcnt(0)" ::: "memory");
  __builtin_amdgcn_sched_barrier(0);
  ISSUE_H(0, hq[0]);
  LDX4P(xbuf[0][0], xq[0], 0); LDX4P(xbuf[0][1], xq[0], 64);

#pragma unroll 1
  for (int t = 0; t < 128; ++t) {
    // keep A-frags register-resident
    asm volatile("" : "+v"(A0[0]), "+v"(A0[1]), "+v"(A0[2]), "+v"(A0[3]),
                      "+v"(A0[4]), "+v"(A0[5]), "+v"(A0[6]), "+v"(A0[7]));
    asm volatile("" : "+v"(A1[0]), "+v"(A1[1]), "+v"(A1[2]), "+v"(A1[3]),
                      "+v"(A1[4]), "+v"(A1[5]), "+v"(A1[6]), "+v"(A1[7]));
    SLOT(0, 1)
    SLOT(1, 2)
    SLOT(2, 3)
    SLOT(3, 0)
  }
}

// ---------------------------------------------------------------------------
// k_wall2: Wall[t*B+b][u] = [h;c] @ Wd + bW.
// h: hx2 u32 = ~(h[m_lo]|h[m_lo+4]<<16), slot t+1; c: cx2 u32 (same pair
// scheme, no inversion), slot t; m_lo = 8*(k2>>2)+(k2&3).
// ---------------------------------------------------------------------------
__global__ void k_wall2(const unsigned* __restrict__ Hxu, const unsigned* __restrict__ Cxu,
                        const float* __restrict__ Wd, const float* __restrict__ bW,
                        float* __restrict__ Wall) {
  int r0 = blockIdx.x * 32;
  int wv = __builtin_amdgcn_readfirstlane(threadIdx.x >> 6);
  int lane = threadIdx.x & 63;
  int u2 = lane * 2;
  int rbase = r0 + wv * 8;
  float acc[8][2];
#pragma unroll
  for (int i = 0; i < 8; i++) { acc[i][0] = 0.f; acc[i][1] = 0.f; }
#pragma unroll 2
  for (int k2 = 0; k2 < 128; ++k2) {
    int m_lo = 8 * (k2 >> 2) + (k2 & 3);
    float2 wh0 = *(const float2*)(Wd + (size_t)m_lo * Tc + u2);
    float2 wh1 = *(const float2*)(Wd + (size_t)(m_lo + 4) * Tc + u2);
    float2 wc0 = *(const float2*)(Wd + (size_t)(Mc + m_lo) * Tc + u2);
    float2 wc1 = *(const float2*)(Wd + (size_t)(Mc + m_lo + 4) * Tc + u2);
#pragma unroll
    for (int i = 0; i < 8; i++) {
      unsigned hraw = ~Hxu[(size_t)(rbase + i) * 128 + 16384 + k2];  // slot t+1
      unsigned craw = Cxu[(size_t)(rbase + i) * 128 + k2];           // slot t
      __half2 hv = __builtin_bit_cast(__half2, hraw);
      __half2 cv = __builtin_bit_cast(__half2, craw);
      float hlo = __low2float(hv), hhi = __high2float(hv);
      float clo = __low2float(cv), chi = __high2float(cv);
      acc[i][0] += hlo * wh0.x + hhi * wh1.x + clo * wc0.x + chi * wc1.x;
      acc[i][1] += hlo * wh0.y + hhi * wh1.y + clo * wc0.y + chi * wc1.y;
    }
  }
  float bw0 = bW[u2], bw1 = bW[u2 + 1];
#pragma unroll
  for (int i = 0; i < 8; i++) {
    float2 o; o.x = acc[i][0] + bw0; o.y = acc[i][1] + bw1;
    *(float2*)(Wall + (size_t)(rbase + i) * Tc + u2) = o;
  }
}

// ---------------------------------------------------------------------------
// k_attn: logits_n = sum_u (-2 v_u) / (A_u * P_un + 1); softmax; out = X*alpha
// ---------------------------------------------------------------------------
__global__ void k_attn(const float* __restrict__ Wall, const float* __restrict__ PX,
                       const float* __restrict__ vd, const float* __restrict__ X,
                       float* __restrict__ out) {
  __shared__ float4 av[Nc];
  __shared__ float v2s[Nc];
  __shared__ float wred[2][4];
  int b = blockIdx.x & 127, tq = blockIdx.x >> 7;
  int n = threadIdx.x;           // 0..127
  int wv = n >> 6;
  float4 a;
  a.x = __expf(2.f * Wall[((size_t)(tq * 4 + 0) * Bc + b) * Tc + n]);
  a.y = __expf(2.f * Wall[((size_t)(tq * 4 + 1) * Bc + b) * Tc + n]);
  a.z = __expf(2.f * Wall[((size_t)(tq * 4 + 2) * Bc + b) * Tc + n]);
  a.w = __expf(2.f * Wall[((size_t)(tq * 4 + 3) * Bc + b) * Tc + n]);
  av[n] = a;
  v2s[n] = -2.f * vd[n];
  __syncthreads();
  const float* Pb = PX + (size_t)b * Tc * Nc;
  float e0 = 0.f, e1 = 0.f, e2 = 0.f, e3 = 0.f;
#pragma unroll 4
  for (int u = 0; u < Tc; ++u) {
    float P = Pb[(size_t)u * Nc + n];
    float4 au = av[u];
    float v2 = v2s[u];
    e0 = fmaf(v2, frcp(fmaf(au.x, P, 1.f)), e0);
    e1 = fmaf(v2, frcp(fmaf(au.y, P, 1.f)), e1);
    e2 = fmaf(v2, frcp(fmaf(au.z, P, 1.f)), e2);
    e3 = fmaf(v2, frcp(fmaf(au.w, P, 1.f)), e3);
  }
  float e[4] = {e0, e1, e2, e3};
  float M[4], S[4], ex[4];
#pragma unroll
  for (int k = 0; k < 4; ++k) {
    float m = e[k];
#pragma unroll
    for (int off = 32; off > 0; off >>= 1) m = fmaxf(m, __shfl_xor(m, off));
    if ((n & 63) == 0) wred[wv][k] = m;
  }
  __syncthreads();
#pragma unroll
  for (int k = 0; k < 4; ++k) M[k] = fmaxf(wred[0][k], wred[1][k]);
  __syncthreads();
#pragma unroll
  for (int k = 0; k < 4; ++k) {
    ex[k] = __expf(e[k] - M[k]);
    float s = ex[k];
#pragma unroll
    for (int off = 32; off > 0; off >>= 1) s += __shfl_xor(s, off);
    if ((n & 63) == 0) wred[wv][k] = s;
  }
  __syncthreads();
#pragma unroll
  for (int k = 0; k < 4; ++k) S[k] = wred[0][k] + wred[1][k];
#pragma unroll
  for (int k = 0; k < 4; ++k) {
    int t = tq * 4 + k;
    size_t xi = ((size_t)b * Tc + t) * Nc + n;
    out[xi] = X[xi] * (ex[k] * frcp(S[k]));
  }
}

extern "C" void kernel_launch(void* const* d_in, const int* in_sizes, int n_in,
                              void* d_out, int out_size, void* d_ws, size_t ws_size,
                              hipStream_t stream) {
  (void)in_sizes; (void)n_in; (void)out_size; (void)ws_size;
  const float* X  = (const float*)d_in[0];
  const float* h0 = (const float*)d_in[1];
  const float* s0 = (const float*)d_in[2];
  const float* Wx = (const float*)d_in[3];
  const float* Wh = (const float*)d_in[4];
  const float* bb = (const float*)d_in[5];
  const float* Wd = (const float*)d_in[6];
  const float* bW = (const float*)d_in[7];
  const float* Ud = (const float*)d_in[8];
  const float* bU = (const float*)d_in[9];
  const float* vd = (const float*)d_in[10];
  // d_in[11] = bv: softmax(x + const) == softmax(x), no effect on output.
  float* out = (float*)d_out;
  float* ws = (float*)d_ws;

  float* PX       = ws;                          //  2,097,152 f
  float* XWxP     = PX + 2097152;                // 16,777,216 f
  unsigned* hx2   = (unsigned*)(XWxP + 16777216);// 129*16384 u32 (~h pairs)
  unsigned* cx2   = hx2 + 129 * 16384;           // 128*16384 u32 (c pairs)
  float* Wall     = (float*)(cx2 + 128 * 16384); //  2,097,152 f
  __half* wht     = (__half*)(Wall + 2097152);   //   262,144 halves
  // total ~101 MB

  k_prep<<<8768, 256, 0, stream>>>(Wh, h0, wht, hx2);
  k_ux<<<Bc, 256, 0, stream>>>(X, Ud, bU, PX);
  k_xwx2<<<Tc * 4, 256, 0, stream>>>(X, Wx, bb, XWxP);
  k_scan<<<8, 512, 0, stream>>>(wht, XWxP, hx2, cx2, s0);
  k_wall2<<<(Tc * Bc) / 32, 256, 0, stream>>>(hx2, cx2, Wd, bW, Wall);
  k_attn<<<Bc * 32, 128, 0, stream>>>(Wall, PX, vd, X, out);
}

// Round 10
// 830.817 us; speedup vs baseline: 2.4759x; 2.4759x over previous
//
#include <hip/hip_runtime.h>
#include <hip/hip_fp16.h>

// Problem dims (fixed)
#define Bc 128   // batch
#define Tc 128   // timesteps
#define Nc 128   // driving series
#define Mc 256   // hidden
#define G4 1024  // 4*M

typedef _Float16 half8 __attribute__((ext_vector_type(8)));
typedef float f32x4 __attribute__((ext_vector_type(4)));
typedef unsigned u32x4 __attribute__((ext_vector_type(4)));

__device__ __forceinline__ float frcp(float x) {
#if __has_builtin(__builtin_amdgcn_rcpf)
  return __builtin_amdgcn_rcpf(x);
#else
  return 1.f / x;
#endif
}
__device__ __forceinline__ float fsig(float x) { return frcp(1.f + __expf(-x)); }
__device__ __forceinline__ float ftanh(float x) {
  float t = __expf(2.f * x);
  return 1.f - 2.f * frcp(t + 1.f);
}

// gfx950: offset:N must precede cache flags
#define LDX4CC(dst, ptr, OFF) \
  asm volatile("global_load_dwordx4 %0, %1, off offset:" #OFF " sc0 sc1" \
               : "=v"(dst) : "v"(ptr))
// publish via atomic swap: executes at the coherence point (IF$), leaves the
// line L3-resident (unlike an sc0sc1 write-through store). No return (no sc0),
// relaxed (no cache maintenance), zero contention (each lane owns its dword).
#define ATOMSW(ptr, v_) \
  asm volatile("global_atomic_swap %0, %1, off" :: "v"(ptr), "v"(v_) : "memory")
#define VMCNT0 do { asm volatile("s_waitcnt vmcnt(0)" ::: "memory"); \
                    __builtin_amdgcn_sched_barrier(0); } while (0)

// ---------------------------------------------------------------------------
// k_prep (8768 blocks x 256):
//  bid<512   : pack Wh -> fp16 A-frags, gate-interleaved cols j'=4m+g, and
//              k-pair order (r2, r2+4) matching the B-side u32 (m, m+4) pairs.
//  512..575  : hx2[0] = ~pack(fp16(h0))  (u32 i=4a+d <-> halves (8a+d, 8a+d+4))
//  576..8767 : zero hx2[1..128]  (poll sentinel; re-zeroed EVERY launch)
// ---------------------------------------------------------------------------
__global__ void k_prep(const float* __restrict__ Wh, const float* __restrict__ h0,
                       __half* __restrict__ wht, unsigned* __restrict__ hx2) {
  int bid = blockIdx.x;
  if (bid < 512) {
    int i = bid * 256 + threadIdx.x;       // u32 index in [0, 131072)
    int jt = i >> 11;
    int rem = i & 2047;
    int kt = rem >> 8;
    int rem2 = rem & 255;
    int lane = rem2 >> 2;
    int r2 = rem2 & 3;
    int jp = jt * 16 + (lane & 15);        // permuted col j'
    int g = jp & 3, mcol = jp >> 2;
    int j = g * 256 + mcol;                // original Wh column
    int mk0 = kt * 32 + (lane >> 4) * 8 + r2;   // k-pair (r2, r2+4)
    wht[(size_t)i * 2]     = __float2half(Wh[(size_t)mk0 * G4 + j]);
    wht[(size_t)i * 2 + 1] = __float2half(Wh[(size_t)(mk0 + 4) * G4 + j]);
  } else if (bid < 576) {
    int idx = (bid - 512) * 256 + threadIdx.x;   // 0..16383
    int b = idx >> 7, i = idx & 127;
    int a = i >> 2, d = i & 3;
    unsigned lo = __half_as_ushort(__float2half(h0[(size_t)b * Mc + 8 * a + d]));
    unsigned hi = __half_as_ushort(__float2half(h0[(size_t)b * Mc + 8 * a + d + 4]));
    hx2[idx] = ~(lo | (hi << 16));
  } else {
    int idx = (bid - 576) * 256 + threadIdx.x;   // 0..2097151
    hx2[16384 + idx] = 0u;
  }
}

// ---------------------------------------------------------------------------
// k_ux: PX[b][u][n] = exp(2*(sum_t X[b][t][n]*Ud[t][u] + bU[u]))
// ---------------------------------------------------------------------------
__global__ void k_ux(const float* __restrict__ X, const float* __restrict__ Ud,
                     const float* __restrict__ bU, float* __restrict__ PX) {
  __shared__ float Xl[Tc][Nc];  // 64KB
  int b = blockIdx.x;
  const float* Xb = X + (size_t)b * Tc * Nc;
  for (int i = threadIdx.x; i < Tc * Nc; i += 256) Xl[i >> 7][i & 127] = Xb[i];
  __syncthreads();
  int n = threadIdx.x & 127;
  int uh = __builtin_amdgcn_readfirstlane(threadIdx.x >> 7);
  for (int u0 = uh * 64; u0 < uh * 64 + 64; u0 += 8) {
    float acc[8];
#pragma unroll
    for (int i = 0; i < 8; i++) acc[i] = 0.f;
    for (int tt = 0; tt < Tc; ++tt) {
      float xv = Xl[tt][n];
#pragma unroll
      for (int i = 0; i < 8; i++) acc[i] += xv * Ud[tt * Tc + u0 + i];
    }
#pragma unroll
    for (int i = 0; i < 8; i++)
      PX[((size_t)b * Tc + (u0 + i)) * Nc + n] = __expf(2.f * (acc[i] + bU[u0 + i]));
  }
}

// ---------------------------------------------------------------------------
// k_xwx2: XWxP[t][b][j'] with j' = 4m+g. grid 512 = t(128) x bq(4), 256 thr.
// ---------------------------------------------------------------------------
__global__ __launch_bounds__(256, 2)
void k_xwx2(const float* __restrict__ X, const float* __restrict__ Wx,
            const float* __restrict__ bias, float* __restrict__ XWxP) {
  __shared__ float xl[32][Nc];  // 16KB
  int t = blockIdx.x >> 2;
  int b0 = (blockIdx.x & 3) * 32;
  for (int i = threadIdx.x; i < 32 * Nc; i += 256) {
    int row = i >> 7, n = i & 127;
    xl[row][n] = X[(size_t)(b0 + row) * Tc * Nc + (size_t)t * Nc + n];
  }
  __syncthreads();
  int m = threadIdx.x;
  float acc[32][4];
#pragma unroll
  for (int i = 0; i < 32; i++)
#pragma unroll
    for (int g = 0; g < 4; g++) acc[i][g] = 0.f;
  for (int n = 0; n < Nc; ++n) {
    float wi = Wx[(size_t)n * G4 + m];
    float wf = Wx[(size_t)n * G4 + 256 + m];
    float wg = Wx[(size_t)n * G4 + 512 + m];
    float wo = Wx[(size_t)n * G4 + 768 + m];
#pragma unroll
    for (int i = 0; i < 32; i++) {
      float xv = xl[i][n];
      acc[i][0] += xv * wi; acc[i][1] += xv * wf;
      acc[i][2] += xv * wg; acc[i][3] += xv * wo;
    }
  }
  float bi = bias[m], bf = bias[256 + m], bg = bias[512 + m], bo = bias[768 + m];
#pragma unroll
  for (int i = 0; i < 32; i++) {
    float4 o;
    o.x = acc[i][0] + bi; o.y = acc[i][1] + bf;
    o.z = acc[i][2] + bg; o.w = acc[i][3] + bo;
    *(float4*)(XWxP + ((size_t)t * Bc + b0 + i) * G4 + m * 4) = o;
  }
}

// ---------------------------------------------------------------------------
// k_scan: persistent LSTM scan, 32 blocks x 512 threads (r8 structure —
// proven 600us; the macro-pipelines of r5/r9 spilled and regressed).
// DATA-IS-FLAG sync: h published as ONE dword/lane = ~(h[m]|h[m+4]<<16) at
// hx2[t+1][b][jt0*2+lg] via GLOBAL_ATOMIC_SWAP (lands at IF$; r8's sc0sc1
// store wrote through past L3 -> consumer polls paid HBM latency). Slot
// pre-zeroed; consumer polls its 8 dwordx4 sc0sc1 loads until every dword
// != 0, then uses ~data. ~pack==0 would require NaN h: impossible.
// ---------------------------------------------------------------------------
__global__ __launch_bounds__(512, 2)
void k_scan(const __half* __restrict__ wht, const float* __restrict__ xwxp,
            unsigned* __restrict__ hx2, __half* __restrict__ cx,
            const float* __restrict__ s0) {
  int bid = blockIdx.x;                 // 32 blocks
  int q = bid >> 3, grp = bid & 7;
  int tid = threadIdx.x;
  int wave = __builtin_amdgcn_readfirstlane(tid >> 6);
  int lane = tid & 63;
  int lb = lane & 15, lg = lane >> 4;
  int b = grp * 16 + lb;
  int jt0 = q * 16 + wave * 2;          // even
  int m0 = jt0 * 4 + lg;

  // persistent A fragments: 64 VGPRs, loaded once
  half8 A0[8], A1[8];
#pragma unroll
  for (int kt = 0; kt < 8; ++kt) {
    A0[kt] = *(const half8*)(wht + ((size_t)(jt0 * 8 + kt) * 64 + lane) * 8);
    A1[kt] = *(const half8*)(wht + ((size_t)((jt0 + 1) * 8 + kt) * 64 + lane) * 8);
  }

  float c0 = s0[(size_t)b * Mc + m0];
  float c1 = s0[(size_t)b * Mc + m0 + 4];

  const char* hq = (const char*)hx2 + ((size_t)b * 128 + lg * 4) * 4;         // read h[t]
  char*       hs = (char*)hx2 + ((size_t)16384 + b * 128 + jt0 * 2 + lg) * 4; // write h[t+1]
  const float* xq = xwxp + ((size_t)b) * G4 + jt0 * 16 + lg * 4;
  __half*      cq = cx + (size_t)b * Mc;

  f32x4 braw[8];

#pragma unroll 1
  for (int t = 0; t < 128; ++t) {
    // PIN: force A-frags to stay register-resident
    asm volatile("" : "+v"(A0[0]), "+v"(A0[1]), "+v"(A0[2]), "+v"(A0[3]),
                      "+v"(A0[4]), "+v"(A0[5]), "+v"(A0[6]), "+v"(A0[7]));
    asm volatile("" : "+v"(A1[0]), "+v"(A1[1]), "+v"(A1[2]), "+v"(A1[3]),
                      "+v"(A1[4]), "+v"(A1[5]), "+v"(A1[6]), "+v"(A1[7]));

    // acc init (plain loads, L2)
    f32x4 acc0 = *(const f32x4*)(xq);
    f32x4 acc1 = *(const f32x4*)(xq + 16);

    // poll-load h[t]: data IS the flag
    LDX4CC(braw[0], hq, 0);   LDX4CC(braw[1], hq, 64);
    LDX4CC(braw[2], hq, 128); LDX4CC(braw[3], hq, 192);
    LDX4CC(braw[4], hq, 256); LDX4CC(braw[5], hq, 320);
    LDX4CC(braw[6], hq, 384); LDX4CC(braw[7], hq, 448);
    for (;;) {
      VMCNT0;
      unsigned mn = 0xFFFFFFFFu;
#pragma unroll
      for (int kt = 0; kt < 8; ++kt) {
        u32x4 u = __builtin_bit_cast(u32x4, braw[kt]);
        mn = min(mn, min(min(u.x, u.y), min(u.z, u.w)));
      }
      if (__builtin_expect(mn != 0u, 1)) break;
      LDX4CC(braw[0], hq, 0);   LDX4CC(braw[1], hq, 64);
      LDX4CC(braw[2], hq, 128); LDX4CC(braw[3], hq, 192);
      LDX4CC(braw[4], hq, 256); LDX4CC(braw[5], hq, 320);
      LDX4CC(braw[6], hq, 384); LDX4CC(braw[7], hq, 448);
    }

#pragma unroll
    for (int kt = 0; kt < 8; ++kt) {
      u32x4 u = ~__builtin_bit_cast(u32x4, braw[kt]);
      half8 Bf = __builtin_bit_cast(half8, u);
      acc0 = __builtin_amdgcn_mfma_f32_16x16x32_f16(A0[kt], Bf, acc0, 0, 0, 0);
      acc1 = __builtin_amdgcn_mfma_f32_16x16x32_f16(A1[kt], Bf, acc1, 0, 0, 0);
    }
    // gates: regs 0..3 = (i,f,g,o)
    float i0 = fsig(acc0[0]), f0 = fsig(acc0[1]);
    float g0 = ftanh(acc0[2]), o0 = fsig(acc0[3]);
    c0 = f0 * c0 + i0 * g0;
    float h0v = o0 * ftanh(c0);
    float i1 = fsig(acc1[0]), f1 = fsig(acc1[1]);
    float g1 = ftanh(acc1[2]), o1 = fsig(acc1[3]);
    c1 = f1 * c1 + i1 * g1;
    float h1v = o1 * ftanh(c1);

    unsigned pk = (unsigned)__half_as_ushort(__float2half(h0v)) |
                  ((unsigned)__half_as_ushort(__float2half(h1v)) << 16);
    ATOMSW(hs, ~pk);                       // publish h[t+1] at the IF$

    cq[m0]     = __float2half(c0);         // c: plain lazy stores
    cq[m0 + 4] = __float2half(c1);

    hq += 65536; hs += 65536; xq += Bc * G4; cq += Bc * Mc;
  }
}

// ---------------------------------------------------------------------------
// k_wall2: Wall[t*B+b][u] = [h;c] @ Wd + bW.
// h read from hx2 (u32 = ~(h[m_lo]|h[m_lo+4]<<16), m_lo = 8*(k2>>2)+(k2&3));
// c read from cx (natural half2 pairs (2k2, 2k2+1)).
// ---------------------------------------------------------------------------
__global__ void k_wall2(const unsigned* __restrict__ Hxu, const __half2* __restrict__ Cx2,
                        const float* __restrict__ Wd, const float* __restrict__ bW,
                        float* __restrict__ Wall) {
  int r0 = blockIdx.x * 32;
  int wv = __builtin_amdgcn_readfirstlane(threadIdx.x >> 6);
  int lane = threadIdx.x & 63;
  int u2 = lane * 2;
  int rbase = r0 + wv * 8;
  float acc[8][2];
#pragma unroll
  for (int i = 0; i < 8; i++) { acc[i][0] = 0.f; acc[i][1] = 0.f; }
#pragma unroll 2
  for (int k2 = 0; k2 < 128; ++k2) {
    int m_lo = 8 * (k2 >> 2) + (k2 & 3);
    float2 wh0 = *(const float2*)(Wd + (size_t)m_lo * Tc + u2);
    float2 wh1 = *(const float2*)(Wd + (size_t)(m_lo + 4) * Tc + u2);
    float2 wc0 = *(const float2*)(Wd + (size_t)(Mc + 2 * k2) * Tc + u2);
    float2 wc1 = *(const float2*)(Wd + (size_t)(Mc + 2 * k2 + 1) * Tc + u2);
#pragma unroll
    for (int i = 0; i < 8; i++) {
      unsigned hraw = ~Hxu[(size_t)(rbase + i) * 128 + 16384 + k2];  // slot t+1
      __half2 hv = __builtin_bit_cast(__half2, hraw);
      __half2 cv = Cx2[(size_t)(rbase + i) * 128 + k2];
      float hlo = __low2float(hv), hhi = __high2float(hv);
      float clo = __low2float(cv), chi = __high2float(cv);
      acc[i][0] += hlo * wh0.x + hhi * wh1.x + clo * wc0.x + chi * wc1.x;
      acc[i][1] += hlo * wh0.y + hhi * wh1.y + clo * wc0.y + chi * wc1.y;
    }
  }
  float bw0 = bW[u2], bw1 = bW[u2 + 1];
#pragma unroll
  for (int i = 0; i < 8; i++) {
    float2 o; o.x = acc[i][0] + bw0; o.y = acc[i][1] + bw1;
    *(float2*)(Wall + (size_t)(rbase + i) * Tc + u2) = o;
  }
}

// ---------------------------------------------------------------------------
// k_attn: logits_n = sum_u (-2 v_u) / (A_u * P_un + 1); softmax; out = X*alpha
// FULLY SCALAR state (r8's e[4]/M[4]/S[4]/ex[4] arrays spilled to scratch:
// VGPR_Count=12 -> 83us for ~7us of VALU work).
// ---------------------------------------------------------------------------
__global__ void k_attn(const float* __restrict__ Wall, const float* __restrict__ PX,
                       const float* __restrict__ vd, const float* __restrict__ X,
                       float* __restrict__ out) {
  __shared__ float4 av[Nc];
  __shared__ float v2s[Nc];
  __shared__ float red[2][8];
  int b = blockIdx.x & 127, tq = blockIdx.x >> 7;
  int n = threadIdx.x;           // 0..127
  int wv = n >> 6;
  float4 a;
  a.x = __expf(2.f * Wall[((size_t)(tq * 4 + 0) * Bc + b) * Tc + n]);
  a.y = __expf(2.f * Wall[((size_t)(tq * 4 + 1) * Bc + b) * Tc + n]);
  a.z = __expf(2.f * Wall[((size_t)(tq * 4 + 2) * Bc + b) * Tc + n]);
  a.w = __expf(2.f * Wall[((size_t)(tq * 4 + 3) * Bc + b) * Tc + n]);
  av[n] = a;
  v2s[n] = -2.f * vd[n];
  __syncthreads();
  const float* Pb = PX + (size_t)b * Tc * Nc;
  float e0 = 0.f, e1 = 0.f, e2 = 0.f, e3 = 0.f;
#pragma unroll 4
  for (int u = 0; u < Tc; ++u) {
    float P = Pb[(size_t)u * Nc + n];
    float4 au = av[u];
    float v2 = v2s[u];
    e0 = fmaf(v2, frcp(fmaf(au.x, P, 1.f)), e0);
    e1 = fmaf(v2, frcp(fmaf(au.y, P, 1.f)), e1);
    e2 = fmaf(v2, frcp(fmaf(au.z, P, 1.f)), e2);
    e3 = fmaf(v2, frcp(fmaf(au.w, P, 1.f)), e3);
  }
  // row maxima (4 independent scalar reductions)
  float m0 = e0, m1 = e1, m2 = e2, m3 = e3;
#pragma unroll
  for (int off = 32; off > 0; off >>= 1) {
    m0 = fmaxf(m0, __shfl_xor(m0, off));
    m1 = fmaxf(m1, __shfl_xor(m1, off));
    m2 = fmaxf(m2, __shfl_xor(m2, off));
    m3 = fmaxf(m3, __shfl_xor(m3, off));
  }
  if ((n & 63) == 0) {
    red[wv][0] = m0; red[wv][1] = m1; red[wv][2] = m2; red[wv][3] = m3;
  }
  __syncthreads();
  m0 = fmaxf(red[0][0], red[1][0]);
  m1 = fmaxf(red[0][1], red[1][1]);
  m2 = fmaxf(red[0][2], red[1][2]);
  m3 = fmaxf(red[0][3], red[1][3]);
  float x0 = __expf(e0 - m0);
  float x1 = __expf(e1 - m1);
  float x2 = __expf(e2 - m2);
  float x3 = __expf(e3 - m3);
  float s0 = x0, s1 = x1, s2 = x2, s3 = x3;
#pragma unroll
  for (int off = 32; off > 0; off >>= 1) {
    s0 += __shfl_xor(s0, off);
    s1 += __shfl_xor(s1, off);
    s2 += __shfl_xor(s2, off);
    s3 += __shfl_xor(s3, off);
  }
  if ((n & 63) == 0) {
    red[wv][4] = s0; red[wv][5] = s1; red[wv][6] = s2; red[wv][7] = s3;
  }
  __syncthreads();
  s0 = red[0][4] + red[1][4];
  s1 = red[0][5] + red[1][5];
  s2 = red[0][6] + red[1][6];
  s3 = red[0][7] + red[1][7];
  size_t xi0 = ((size_t)b * Tc + tq * 4) * Nc + n;
  out[xi0]            = X[xi0]            * (x0 * frcp(s0));
  out[xi0 + Nc]       = X[xi0 + Nc]       * (x1 * frcp(s1));
  out[xi0 + 2 * Nc]   = X[xi0 + 2 * Nc]   * (x2 * frcp(s2));
  out[xi0 + 3 * Nc]   = X[xi0 + 3 * Nc]   * (x3 * frcp(s3));
}

extern "C" void kernel_launch(void* const* d_in, const int* in_sizes, int n_in,
                              void* d_out, int out_size, void* d_ws, size_t ws_size,
                              hipStream_t stream) {
  (void)in_sizes; (void)n_in; (void)out_size; (void)ws_size;
  const float* X  = (const float*)d_in[0];
  const float* h0 = (const float*)d_in[1];
  const float* s0 = (const float*)d_in[2];
  const float* Wx = (const float*)d_in[3];
  const float* Wh = (const float*)d_in[4];
  const float* bb = (const float*)d_in[5];
  const float* Wd = (const float*)d_in[6];
  const float* bW = (const float*)d_in[7];
  const float* Ud = (const float*)d_in[8];
  const float* bU = (const float*)d_in[9];
  const float* vd = (const float*)d_in[10];
  // d_in[11] = bv: softmax(x + const) == softmax(x), no effect on output.
  float* out = (float*)d_out;
  float* ws = (float*)d_ws;

  float* PX       = ws;                          //  2,097,152 f
  float* XWxP     = PX + 2097152;                // 16,777,216 f
  unsigned* hx2   = (unsigned*)(XWxP + 16777216);// 129*16384 u32 (~h pairs)
  __half* cx      = (__half*)(hx2 + 129 * 16384);// 128*32768 halves
  float* Wall     = (float*)(cx + 128 * 32768);  //  2,097,152 f
  __half* wht     = (__half*)(Wall + 2097152);   //   262,144 halves
  // total ~101 MB

  k_prep<<<8768, 256, 0, stream>>>(Wh, h0, wht, hx2);
  k_ux<<<Bc, 256, 0, stream>>>(X, Ud, bU, PX);
  k_xwx2<<<Tc * 4, 256, 0, stream>>>(X, Wx, bb, XWxP);
  k_scan<<<32, 512, 0, stream>>>(wht, XWxP, hx2, cx, s0);
  k_wall2<<<(Tc * Bc) / 32, 256, 0, stream>>>(hx2, (const __half2*)cx, Wd, bW, Wall);
  k_attn<<<Bc * 32, 128, 0, stream>>>(Wall, PX, vd, X, out);
}

// Round 11
// 644.055 us; speedup vs baseline: 3.1938x; 1.2900x over previous
//
#include <hip/hip_runtime.h>
#include <hip/hip_fp16.h>

// Problem dims (fixed)
#define Bc 128   // batch
#define Tc 128   // timesteps
#define Nc 128   // driving series
#define Mc 256   // hidden
#define G4 1024  // 4*M

typedef _Float16 half8 __attribute__((ext_vector_type(8)));
typedef float f32x4 __attribute__((ext_vector_type(4)));
typedef unsigned u32x4 __attribute__((ext_vector_type(4)));

__device__ __forceinline__ float frcp(float x) {
#if __has_builtin(__builtin_amdgcn_rcpf)
  return __builtin_amdgcn_rcpf(x);
#else
  return 1.f / x;
#endif
}
__device__ __forceinline__ float fsig(float x) { return frcp(1.f + __expf(-x)); }
__device__ __forceinline__ float ftanh(float x) {
  float t = __expf(2.f * x);
  return 1.f - 2.f * frcp(t + 1.f);
}

// gfx950: offset:N must precede cache flags
#define LDX4CC(dst, ptr, OFF) \
  asm volatile("global_load_dwordx4 %0, %1, off offset:" #OFF " sc0 sc1" \
               : "=v"(dst) : "v"(ptr))
#define LDX4P(dst, ptr, OFF) \
  asm volatile("global_load_dwordx4 %0, %1, off offset:" #OFF \
               : "=v"(dst) : "v"(ptr))
#define ATOMSW(ptr, v_) \
  asm volatile("global_atomic_swap %0, %1, off" :: "v"(ptr), "v"(v_) : "memory")
#define STDWP(ptr, v_) \
  asm volatile("global_store_dword %0, %1, off" :: "v"(ptr), "v"(v_) : "memory")
#define VMCNT0 do { asm volatile("s_waitcnt vmcnt(0)" ::: "memory"); \
                    __builtin_amdgcn_sched_barrier(0); } while (0)

// ---------------------------------------------------------------------------
// k_prep (8769 blocks x 256):
//  bid<512   : pack Wh -> fp16 A-frags (gate-interleaved cols j'=4m+g,
//              k-pair order (r2, r2+4) matching B-side u32 (m, m+4) pairs)
//  512..575  : hx2[0] = ~pack(fp16(h0))
//  576..8767 : zero hx2[1..128]  (slow-path poll sentinel; re-zeroed EVERY launch)
//  8768      : zero flags+xcdtab; preset flag[grp][0]=4 (t=0 ready)
// ---------------------------------------------------------------------------
__global__ void k_prep(const float* __restrict__ Wh, const float* __restrict__ h0,
                       __half* __restrict__ wht, unsigned* __restrict__ hx2,
                       unsigned* __restrict__ flags) {
  int bid = blockIdx.x;
  if (bid < 512) {
    int i = bid * 256 + threadIdx.x;       // u32 index in [0, 131072)
    int jt = i >> 11;
    int rem = i & 2047;
    int kt = rem >> 8;
    int rem2 = rem & 255;
    int lane = rem2 >> 2;
    int r2 = rem2 & 3;
    int jp = jt * 16 + (lane & 15);        // permuted col j'
    int g = jp & 3, mcol = jp >> 2;
    int j = g * 256 + mcol;                // original Wh column
    int mk0 = kt * 32 + (lane >> 4) * 8 + r2;   // k-pair (r2, r2+4)
    wht[(size_t)i * 2]     = __float2half(Wh[(size_t)mk0 * G4 + j]);
    wht[(size_t)i * 2 + 1] = __float2half(Wh[(size_t)(mk0 + 4) * G4 + j]);
  } else if (bid < 576) {
    int idx = (bid - 512) * 256 + threadIdx.x;   // 0..16383
    int b = idx >> 7, i = idx & 127;
    int a = i >> 2, d = i & 3;
    unsigned lo = __half_as_ushort(__float2half(h0[(size_t)b * Mc + 8 * a + d]));
    unsigned hi = __half_as_ushort(__float2half(h0[(size_t)b * Mc + 8 * a + d + 4]));
    hx2[idx] = ~(lo | (hi << 16));
  } else if (bid < 8768) {
    int idx = (bid - 576) * 256 + threadIdx.x;   // 0..2097151
    hx2[16384 + idx] = 0u;
  } else {
    // flags: 8 grp x 129 t x 16 dwords (64B spacing) = 16512; xcdtab: 32
    for (int i = threadIdx.x; i < 16544; i += 256) flags[i] = 0u;
    __syncthreads();
    if (threadIdx.x < 8) flags[threadIdx.x * 129 * 16] = 4u;  // flag[grp][0]=4
  }
}

// ---------------------------------------------------------------------------
// k_ux: PX[b][u][n] = exp(2*(sum_t X[b][t][n]*Ud[t][u] + bU[u]))
// ---------------------------------------------------------------------------
__global__ void k_ux(const float* __restrict__ X, const float* __restrict__ Ud,
                     const float* __restrict__ bU, float* __restrict__ PX) {
  __shared__ float Xl[Tc][Nc];  // 64KB
  int b = blockIdx.x;
  const float* Xb = X + (size_t)b * Tc * Nc;
  for (int i = threadIdx.x; i < Tc * Nc; i += 256) Xl[i >> 7][i & 127] = Xb[i];
  __syncthreads();
  int n = threadIdx.x & 127;
  int uh = __builtin_amdgcn_readfirstlane(threadIdx.x >> 7);
  for (int u0 = uh * 64; u0 < uh * 64 + 64; u0 += 8) {
    float acc[8];
#pragma unroll
    for (int i = 0; i < 8; i++) acc[i] = 0.f;
    for (int tt = 0; tt < Tc; ++tt) {
      float xv = Xl[tt][n];
#pragma unroll
      for (int i = 0; i < 8; i++) acc[i] += xv * Ud[tt * Tc + u0 + i];
    }
#pragma unroll
    for (int i = 0; i < 8; i++)
      PX[((size_t)b * Tc + (u0 + i)) * Nc + n] = __expf(2.f * (acc[i] + bU[u0 + i]));
  }
}

// ---------------------------------------------------------------------------
// k_xwx2: XWxP[t][b][j'] with j' = 4m+g. grid 512 = t(128) x bq(4), 256 thr.
// ---------------------------------------------------------------------------
__global__ __launch_bounds__(256, 2)
void k_xwx2(const float* __restrict__ X, const float* __restrict__ Wx,
            const float* __restrict__ bias, float* __restrict__ XWxP) {
  __shared__ float xl[32][Nc];  // 16KB
  int t = blockIdx.x >> 2;
  int b0 = (blockIdx.x & 3) * 32;
  for (int i = threadIdx.x; i < 32 * Nc; i += 256) {
    int row = i >> 7, n = i & 127;
    xl[row][n] = X[(size_t)(b0 + row) * Tc * Nc + (size_t)t * Nc + n];
  }
  __syncthreads();
  int m = threadIdx.x;
  float acc[32][4];
#pragma unroll
  for (int i = 0; i < 32; i++)
#pragma unroll
    for (int g = 0; g < 4; g++) acc[i][g] = 0.f;
  for (int n = 0; n < Nc; ++n) {
    float wi = Wx[(size_t)n * G4 + m];
    float wf = Wx[(size_t)n * G4 + 256 + m];
    float wg = Wx[(size_t)n * G4 + 512 + m];
    float wo = Wx[(size_t)n * G4 + 768 + m];
#pragma unroll
    for (int i = 0; i < 32; i++) {
      float xv = xl[i][n];
      acc[i][0] += xv * wi; acc[i][1] += xv * wf;
      acc[i][2] += xv * wg; acc[i][3] += xv * wo;
    }
  }
  float bi = bias[m], bf = bias[256 + m], bg = bias[512 + m], bo = bias[768 + m];
#pragma unroll
  for (int i = 0; i < 32; i++) {
    float4 o;
    o.x = acc[i][0] + bi; o.y = acc[i][1] + bf;
    o.z = acc[i][2] + bg; o.w = acc[i][3] + bo;
    *(float4*)(XWxP + ((size_t)t * Bc + b0 + i) * G4 + m * 4) = o;
  }
}

// ---------------------------------------------------------------------------
// k_scan: persistent LSTM scan, 32 blocks x 512 threads.
// Group grp = 4 blocks (q=0..3) at bids ≡ grp (mod 8). r4's deadlock PROVED
// these land on one XCD (fast path was selected); it died on sc0 poll-load
// L1 staleness. This round's same-XCD protocol avoids L1 on every re-read:
//   FAST (same XCD, runtime-verified): data via PLAIN stores/loads (consumer
//   addresses are first-touch per launch -> L1 cold miss -> L2, correct;
//   producer plain stores write through to the shared L2). Ordering: vmcnt(0)
//   + __syncthreads + global_atomic_add flag (atomics execute at L2, never
//   L1). Consumer: per-wave lane0 polls global_atomic_or(addr,0) sc0.
//   SLOW (any placement): exact r10 data-is-flag sc0sc1 protocol (proven).
// ---------------------------------------------------------------------------
template <bool FAST>
__device__ __forceinline__ void scan_body(
    const __half* __restrict__ wht, const float* __restrict__ xwxp,
    unsigned* __restrict__ hx2, __half* __restrict__ cx,
    const float* __restrict__ s0, unsigned* __restrict__ flags,
    int q, int grp, int tid, int lane, int lg, int b, int jt0, int m0) {
  // persistent A fragments: 64 VGPRs, loaded once
  half8 A0[8], A1[8];
#pragma unroll
  for (int kt = 0; kt < 8; ++kt) {
    A0[kt] = *(const half8*)(wht + ((size_t)(jt0 * 8 + kt) * 64 + lane) * 8);
    A1[kt] = *(const half8*)(wht + ((size_t)((jt0 + 1) * 8 + kt) * 64 + lane) * 8);
  }

  float c0 = s0[(size_t)b * Mc + m0];
  float c1 = s0[(size_t)b * Mc + m0 + 4];

  const char* hq = (const char*)hx2 + ((size_t)b * 128 + lg * 4) * 4;         // read h[t]
  char*       hs = (char*)hx2 + ((size_t)16384 + b * 128 + jt0 * 2 + lg) * 4; // write h[t+1]
  const float* xq = xwxp + ((size_t)b) * G4 + jt0 * 16 + lg * 4;
  __half*      cq = cx + (size_t)b * Mc;
  unsigned* flgp = flags + (size_t)grp * 129 * 16;   // flag[t] at flgp + t*16

  f32x4 braw[8];

#pragma unroll 1
  for (int t = 0; t < 128; ++t) {
    // PIN: force A-frags register-resident
    asm volatile("" : "+v"(A0[0]), "+v"(A0[1]), "+v"(A0[2]), "+v"(A0[3]),
                      "+v"(A0[4]), "+v"(A0[5]), "+v"(A0[6]), "+v"(A0[7]));
    asm volatile("" : "+v"(A1[0]), "+v"(A1[1]), "+v"(A1[2]), "+v"(A1[3]),
                      "+v"(A1[4]), "+v"(A1[5]), "+v"(A1[6]), "+v"(A1[7]));

    // acc init (plain loads, L2)
    f32x4 acc0 = *(const f32x4*)(xq);
    f32x4 acc1 = *(const f32x4*)(xq + 16);

    if (FAST) {
      if (t > 0) {
        unsigned ret = 0u;
#pragma unroll 1
        do {
          if (lane == 0)
            asm volatile("global_atomic_or %0, %1, %2, off sc0\n\t"
                         "s_waitcnt vmcnt(0)"
                         : "=v"(ret) : "v"(flgp + t * 16), "v"(0u) : "memory");
          ret = __builtin_amdgcn_readfirstlane(ret);
        } while (ret < 4u);
        __builtin_amdgcn_sched_barrier(0);
      }
      // data: plain loads — first-touch addresses, L1 cold -> L2 (coherent)
      LDX4P(braw[0], hq, 0);   LDX4P(braw[1], hq, 64);
      LDX4P(braw[2], hq, 128); LDX4P(braw[3], hq, 192);
      LDX4P(braw[4], hq, 256); LDX4P(braw[5], hq, 320);
      LDX4P(braw[6], hq, 384); LDX4P(braw[7], hq, 448);
      VMCNT0;
    } else {
      // data-is-flag: poll sc0sc1 loads until every dword nonzero
      LDX4CC(braw[0], hq, 0);   LDX4CC(braw[1], hq, 64);
      LDX4CC(braw[2], hq, 128); LDX4CC(braw[3], hq, 192);
      LDX4CC(braw[4], hq, 256); LDX4CC(braw[5], hq, 320);
      LDX4CC(braw[6], hq, 384); LDX4CC(braw[7], hq, 448);
      for (;;) {
        VMCNT0;
        unsigned mn = 0xFFFFFFFFu;
#pragma unroll
        for (int kt = 0; kt < 8; ++kt) {
          u32x4 u = __builtin_bit_cast(u32x4, braw[kt]);
          mn = min(mn, min(min(u.x, u.y), min(u.z, u.w)));
        }
        if (__builtin_expect(mn != 0u, 1)) break;
        LDX4CC(braw[0], hq, 0);   LDX4CC(braw[1], hq, 64);
        LDX4CC(braw[2], hq, 128); LDX4CC(braw[3], hq, 192);
        LDX4CC(braw[4], hq, 256); LDX4CC(braw[5], hq, 320);
        LDX4CC(braw[6], hq, 384); LDX4CC(braw[7], hq, 448);
      }
    }

#pragma unroll
    for (int kt = 0; kt < 8; ++kt) {
      u32x4 u = ~__builtin_bit_cast(u32x4, braw[kt]);
      half8 Bf = __builtin_bit_cast(half8, u);
      acc0 = __builtin_amdgcn_mfma_f32_16x16x32_f16(A0[kt], Bf, acc0, 0, 0, 0);
      acc1 = __builtin_amdgcn_mfma_f32_16x16x32_f16(A1[kt], Bf, acc1, 0, 0, 0);
    }
    // gates: regs 0..3 = (i,f,g,o)
    float i0 = fsig(acc0[0]), f0 = fsig(acc0[1]);
    float g0 = ftanh(acc0[2]), o0 = fsig(acc0[3]);
    c0 = f0 * c0 + i0 * g0;
    float h0v = o0 * ftanh(c0);
    float i1 = fsig(acc1[0]), f1 = fsig(acc1[1]);
    float g1 = ftanh(acc1[2]), o1 = fsig(acc1[3]);
    c1 = f1 * c1 + i1 * g1;
    float h1v = o1 * ftanh(c1);

    unsigned pk = (unsigned)__half_as_ushort(__float2half(h0v)) |
                  ((unsigned)__half_as_ushort(__float2half(h1v)) << 16);
    if (FAST) {
      STDWP(hs, ~pk);                      // plain store -> shared L2
      cq[m0]     = __float2half(c0);
      cq[m0 + 4] = __float2half(c1);
      VMCNT0;                              // h (and c) stores acked by L2
      __syncthreads();                     // ...for all waves
      if (tid == 0)
        asm volatile("global_atomic_add %0, %1, off"
                     :: "v"(flgp + (t + 1) * 16), "v"(1u) : "memory");
    } else {
      ATOMSW(hs, ~pk);                     // publish at coherence point
      cq[m0]     = __float2half(c0);
      cq[m0 + 4] = __float2half(c1);
    }

    hq += 65536; hs += 65536; xq += Bc * G4; cq += Bc * Mc;
  }
}

__global__ __launch_bounds__(512, 2)
void k_scan(const __half* __restrict__ wht, const float* __restrict__ xwxp,
            unsigned* __restrict__ hx2, __half* __restrict__ cx,
            const float* __restrict__ s0, unsigned* __restrict__ flags) {
  int bid = blockIdx.x;                 // 32 blocks
  int q = bid >> 3, grp = bid & 7;
  int tid = threadIdx.x;
  int lane = tid & 63;
  int lb = lane & 15, lg = lane >> 4;
  int b = grp * 16 + lb;
  int jt0 = q * 16 + (tid >> 6) * 2;    // even
  int m0 = jt0 * 4 + lg;

  // placement handshake (r3-proven): fast iff all 4 group members share an XCD
  unsigned* xcdtab = flags + 16512;
  __shared__ int s_fast;
  if (tid == 0) {
    unsigned xcd;
    asm volatile("s_getreg_b32 %0, hwreg(HW_REG_XCC_ID)" : "=s"(xcd));
    asm volatile("global_store_dword %0, %1, off sc0 sc1"
                 :: "v"(xcdtab + bid), "v"(xcd + 1u) : "memory");
    unsigned ref = 0; int fast = 1;
#pragma unroll 1
    for (int k = 0; k < 4; ++k) {
      unsigned v;
      do {
        asm volatile("global_load_dword %0, %1, off sc0 sc1\n\t"
                     "s_waitcnt vmcnt(0)"
                     : "=v"(v) : "v"(xcdtab + (k * 8 + grp)) : "memory");
      } while (v == 0u);
      if (k == 0) ref = v; else fast &= (v == ref) ? 1 : 0;
    }
    s_fast = fast;
  }
  __syncthreads();

  if (s_fast)
    scan_body<true>(wht, xwxp, hx2, cx, s0, flags, q, grp, tid, lane, lg, b, jt0, m0);
  else
    scan_body<false>(wht, xwxp, hx2, cx, s0, flags, q, grp, tid, lane, lg, b, jt0, m0);
}

// ---------------------------------------------------------------------------
// k_wall2: Wall[t*B+b][u] = [h;c] @ Wd + bW.
// h read from hx2 (u32 = ~(h[m_lo]|h[m_lo+4]<<16), m_lo = 8*(k2>>2)+(k2&3));
// c read from cx (natural half2 pairs (2k2, 2k2+1)).
// ---------------------------------------------------------------------------
__global__ void k_wall2(const unsigned* __restrict__ Hxu, const __half2* __restrict__ Cx2,
                        const float* __restrict__ Wd, const float* __restrict__ bW,
                        float* __restrict__ Wall) {
  int r0 = blockIdx.x * 32;
  int wv = __builtin_amdgcn_readfirstlane(threadIdx.x >> 6);
  int lane = threadIdx.x & 63;
  int u2 = lane * 2;
  int rbase = r0 + wv * 8;
  float acc[8][2];
#pragma unroll
  for (int i = 0; i < 8; i++) { acc[i][0] = 0.f; acc[i][1] = 0.f; }
#pragma unroll 2
  for (int k2 = 0; k2 < 128; ++k2) {
    int m_lo = 8 * (k2 >> 2) + (k2 & 3);
    float2 wh0 = *(const float2*)(Wd + (size_t)m_lo * Tc + u2);
    float2 wh1 = *(const float2*)(Wd + (size_t)(m_lo + 4) * Tc + u2);
    float2 wc0 = *(const float2*)(Wd + (size_t)(Mc + 2 * k2) * Tc + u2);
    float2 wc1 = *(const float2*)(Wd + (size_t)(Mc + 2 * k2 + 1) * Tc + u2);
#pragma unroll
    for (int i = 0; i < 8; i++) {
      unsigned hraw = ~Hxu[(size_t)(rbase + i) * 128 + 16384 + k2];  // slot t+1
      __half2 hv = __builtin_bit_cast(__half2, hraw);
      __half2 cv = Cx2[(size_t)(rbase + i) * 128 + k2];
      float hlo = __low2float(hv), hhi = __high2float(hv);
      float clo = __low2float(cv), chi = __high2float(cv);
      acc[i][0] += hlo * wh0.x + hhi * wh1.x + clo * wc0.x + chi * wc1.x;
      acc[i][1] += hlo * wh0.y + hhi * wh1.y + clo * wc0.y + chi * wc1.y;
    }
  }
  float bw0 = bW[u2], bw1 = bW[u2 + 1];
#pragma unroll
  for (int i = 0; i < 8; i++) {
    float2 o; o.x = acc[i][0] + bw0; o.y = acc[i][1] + bw1;
    *(float2*)(Wall + (size_t)(rbase + i) * Tc + u2) = o;
  }
}

// ---------------------------------------------------------------------------
// k_attn: logits_n = sum_u (-2 v_u) / (A_u * P_un + 1); softmax; out = X*alpha
// ---------------------------------------------------------------------------
__global__ void k_attn(const float* __restrict__ Wall, const float* __restrict__ PX,
                       const float* __restrict__ vd, const float* __restrict__ X,
                       float* __restrict__ out) {
  __shared__ float4 av[Nc];
  __shared__ float v2s[Nc];
  __shared__ float red[2][8];
  int b = blockIdx.x & 127, tq = blockIdx.x >> 7;
  int n = threadIdx.x;           // 0..127
  int wv = n >> 6;
  float4 a;
  a.x = __expf(2.f * Wall[((size_t)(tq * 4 + 0) * Bc + b) * Tc + n]);
  a.y = __expf(2.f * Wall[((size_t)(tq * 4 + 1) * Bc + b) * Tc + n]);
  a.z = __expf(2.f * Wall[((size_t)(tq * 4 + 2) * Bc + b) * Tc + n]);
  a.w = __expf(2.f * Wall[((size_t)(tq * 4 + 3) * Bc + b) * Tc + n]);
  av[n] = a;
  v2s[n] = -2.f * vd[n];
  __syncthreads();
  const float* Pb = PX + (size_t)b * Tc * Nc;
  float e0 = 0.f, e1 = 0.f, e2 = 0.f, e3 = 0.f;
#pragma unroll 4
  for (int u = 0; u < Tc; ++u) {
    float P = Pb[(size_t)u * Nc + n];
    float4 au = av[u];
    float v2 = v2s[u];
    e0 = fmaf(v2, frcp(fmaf(au.x, P, 1.f)), e0);
    e1 = fmaf(v2, frcp(fmaf(au.y, P, 1.f)), e1);
    e2 = fmaf(v2, frcp(fmaf(au.z, P, 1.f)), e2);
    e3 = fmaf(v2, frcp(fmaf(au.w, P, 1.f)), e3);
  }
  float m0 = e0, m1 = e1, m2 = e2, m3 = e3;
#pragma unroll
  for (int off = 32; off > 0; off >>= 1) {
    m0 = fmaxf(m0, __shfl_xor(m0, off));
    m1 = fmaxf(m1, __shfl_xor(m1, off));
    m2 = fmaxf(m2, __shfl_xor(m2, off));
    m3 = fmaxf(m3, __shfl_xor(m3, off));
  }
  if ((n & 63) == 0) {
    red[wv][0] = m0; red[wv][1] = m1; red[wv][2] = m2; red[wv][3] = m3;
  }
  __syncthreads();
  m0 = fmaxf(red[0][0], red[1][0]);
  m1 = fmaxf(red[0][1], red[1][1]);
  m2 = fmaxf(red[0][2], red[1][2]);
  m3 = fmaxf(red[0][3], red[1][3]);
  float x0 = __expf(e0 - m0);
  float x1 = __expf(e1 - m1);
  float x2 = __expf(e2 - m2);
  float x3 = __expf(e3 - m3);
  float s0 = x0, s1 = x1, s2 = x2, s3 = x3;
#pragma unroll
  for (int off = 32; off > 0; off >>= 1) {
    s0 += __shfl_xor(s0, off);
    s1 += __shfl_xor(s1, off);
    s2 += __shfl_xor(s2, off);
    s3 += __shfl_xor(s3, off);
  }
  if ((n & 63) == 0) {
    red[wv][4] = s0; red[wv][5] = s1; red[wv][6] = s2; red[wv][7] = s3;
  }
  __syncthreads();
  s0 = red[0][4] + red[1][4];
  s1 = red[0][5] + red[1][5];
  s2 = red[0][6] + red[1][6];
  s3 = red[0][7] + red[1][7];
  size_t xi0 = ((size_t)b * Tc + tq * 4) * Nc + n;
  out[xi0]            = X[xi0]            * (x0 * frcp(s0));
  out[xi0 + Nc]       = X[xi0 + Nc]       * (x1 * frcp(s1));
  out[xi0 + 2 * Nc]   = X[xi0 + 2 * Nc]   * (x2 * frcp(s2));
  out[xi0 + 3 * Nc]   = X[xi0 + 3 * Nc]   * (x3 * frcp(s3));
}

extern "C" void kernel_launch(void* const* d_in, const int* in_sizes, int n_in,
                              void* d_out, int out_size, void* d_ws, size_t ws_size,
                              hipStream_t stream) {
  (void)in_sizes; (void)n_in; (void)out_size; (void)ws_size;
  const float* X  = (const float*)d_in[0];
  const float* h0 = (const float*)d_in[1];
  const float* s0 = (const float*)d_in[2];
  const float* Wx = (const float*)d_in[3];
  const float* Wh = (const float*)d_in[4];
  const float* bb = (const float*)d_in[5];
  const float* Wd = (const float*)d_in[6];
  const float* bW = (const float*)d_in[7];
  const float* Ud = (const float*)d_in[8];
  const float* bU = (const float*)d_in[9];
  const float* vd = (const float*)d_in[10];
  // d_in[11] = bv: softmax(x + const) == softmax(x), no effect on output.
  float* out = (float*)d_out;
  float* ws = (float*)d_ws;

  float* PX       = ws;                          //  2,097,152 f
  float* XWxP     = PX + 2097152;                // 16,777,216 f
  unsigned* hx2   = (unsigned*)(XWxP + 16777216);// 129*16384 u32 (~h pairs)
  __half* cx      = (__half*)(hx2 + 129 * 16384);// 128*32768 halves
  float* Wall     = (float*)(cx + 128 * 32768);  //  2,097,152 f
  __half* wht     = (__half*)(Wall + 2097152);   //   262,144 halves
  unsigned* flags = (unsigned*)(wht + 262144);   // 16512 flags + 32 xcdtab
  // total ~101 MB

  k_prep<<<8769, 256, 0, stream>>>(Wh, h0, wht, hx2, flags);
  k_ux<<<Bc, 256, 0, stream>>>(X, Ud, bU, PX);
  k_xwx2<<<Tc * 4, 256, 0, stream>>>(X, Wx, bb, XWxP);
  k_scan<<<32, 512, 0, stream>>>(wht, XWxP, hx2, cx, s0, flags);
  k_wall2<<<(Tc * Bc) / 32, 256, 0, stream>>>(hx2, (const __half2*)cx, Wd, bW, Wall);
  k_attn<<<Bc * 32, 128, 0, stream>>>(Wall, PX, vd, X, out);
}